// Round 4
// baseline (26665.326 us; speedup 1.0000x reference)
//
#include <hip/hip_runtime.h>
#include <math.h>

// Problem constants: B=8, C=128, H=W=64, NC=64, NH=4, HC=16, KS=4,
// Hk=Wk=16, Ns=256, HW=4096, NB=3 blocks: (i,j) = (1,0),(2,0),(2,1)

typedef _Float16 f16x4 __attribute__((ext_vector_type(4)));
typedef float f32x4 __attribute__((ext_vector_type(4)));
typedef _Float16 h2v __attribute__((ext_vector_type(2)));

// ---- copy: level0 full + level1/2 channels 0..63 (64..127 written by k_po)
__global__ __launch_bounds__(256) void k_copy(
    const float* __restrict__ x0, const float* __restrict__ x1,
    const float* __restrict__ x2, float* __restrict__ out) {
  int i = blockIdx.x * 256 + threadIdx.x;       // f4 idx, total 2097152
  const float4* x0f = (const float4*)x0;
  const float4* x1f = (const float4*)x1;
  const float4* x2f = (const float4*)x2;
  float4 v;
  int oidx;
  if (i < 1048576) {
    oidx = i;
    v = x0f[i];
  } else {
    int j = i - 1048576;
    int half = j >> 19;          // 0 -> level1, 1 -> level2
    int r = j & 524287;
    int bb = r >> 16;
    int off = r & 65535;         // f4 within b's c<64 block
    v = (half == 0) ? x1f[bb * 131072 + off] : x2f[bb * 131072 + off];
    oidx = ((half + 1) * 8 + bb) * 131072 + off;
  }
  ((float4*)out)[oidx] = v;
}

// ------------------------------------------------- q = pq_w @ x_i[:, :64] + b
// grid 768 = 3 num * 8 b * 32 tiles(128 pos); 256 thr: 2 pos x 16 out each
__global__ __launch_bounds__(256) void k_qconv(
    const float* __restrict__ x1, const float* __restrict__ x2,
    const float* __restrict__ pq_w, const float* __restrict__ pq_b,
    float* __restrict__ q_buf) {
  int wg = blockIdx.x;
  int tile = wg & 31;
  int b = (wg >> 5) & 7;
  int num = wg >> 8;
  const float* xin = (num == 0) ? x1 : x2;
  const float* xbase = xin + b * 524288;
  const float* w = pq_w + num * 4096;
  int p0 = tile * 128;
  int tid = threadIdx.x;
  int lane = tid & 63;
  int og = __builtin_amdgcn_readfirstlane(tid >> 6);
  int o0 = og * 16;
  __shared__ float lx[16 * 128];
  float acc[2][16];
#pragma unroll
  for (int j = 0; j < 2; ++j)
#pragma unroll
    for (int i = 0; i < 16; ++i) acc[j][i] = 0.f;
  for (int cc = 0; cc < 64; cc += 16) {
    __syncthreads();
#pragma unroll
    for (int r = 0; r < 2; ++r) {
      int idx = tid + r * 256;                 // 512 f4 = 16 rows x 32 f4
      int c = idx >> 5, col4 = idx & 31;
      *(float4*)(lx + c * 128 + col4 * 4) =
          *(const float4*)(xbase + (cc + c) * 4096 + p0 + col4 * 4);
    }
    __syncthreads();
#pragma unroll
    for (int c = 0; c < 16; ++c) {
      float2 xv = *(const float2*)(lx + c * 128 + lane * 2);
#pragma unroll
      for (int i = 0; i < 16; ++i) {
        float wv = w[(o0 + i) * 64 + cc + c];  // uniform -> s_load
        acc[0][i] += xv.x * wv;
        acc[1][i] += xv.y * wv;
      }
    }
  }
  float* qb = q_buf + (num * 8 + b) * 262144;
#pragma unroll
  for (int i = 0; i < 16; ++i) {
    int o = o0 + i;
    float bias = pq_b[num * 64 + o];
    float2 r2 = {acc[0][i] + bias, acc[1][i] + bias};
    *(float2*)(qb + o * 4096 + p0 + lane * 2) = r2;
  }
}

// ---------------- offset head: depthwise 4x4 s4 + LN + GELU + proj -> pos
__global__ __launch_bounds__(256) void k_offset(
    const float* __restrict__ q_buf, const float* __restrict__ dw_w,
    const float* __restrict__ dw_b, const float* __restrict__ ln_g,
    const float* __restrict__ ln_b, const float* __restrict__ pw_w,
    float* __restrict__ pos_buf) {
  int wg = blockIdx.x;
  int num = wg >> 3;
  int n = threadIdx.x;
  int oy = n >> 4, ox = n & 15;
  const float* qb = q_buf + wg * 262144;
  float off[64];
  float sum = 0.f, sumsq = 0.f;
#pragma unroll
  for (int c = 0; c < 64; ++c) {
    const float* wp = dw_w + (num * 64 + c) * 16;
    const float* qp = qb + c * 4096 + oy * 256 + ox * 4;
    float4 r0 = *(const float4*)(qp);
    float4 r1 = *(const float4*)(qp + 64);
    float4 r2 = *(const float4*)(qp + 128);
    float4 r3 = *(const float4*)(qp + 192);
    float s = dw_b[num * 64 + c];
    s += wp[0] * r0.x + wp[1] * r0.y + wp[2] * r0.z + wp[3] * r0.w;
    s += wp[4] * r1.x + wp[5] * r1.y + wp[6] * r1.z + wp[7] * r1.w;
    s += wp[8] * r2.x + wp[9] * r2.y + wp[10] * r2.z + wp[11] * r2.w;
    s += wp[12] * r3.x + wp[13] * r3.y + wp[14] * r3.z + wp[15] * r3.w;
    off[c] = s;
    sum += s;
    sumsq += s * s;
  }
  float mu = sum * 0.015625f;
  float var = sumsq * 0.015625f - mu * mu;
  float rstd = rsqrtf(var + 1e-5f);
  float offy = 0.f, offx = 0.f;
#pragma unroll
  for (int c = 0; c < 64; ++c) {
    float g = (off[c] - mu) * rstd * ln_g[num * 64 + c] + ln_b[num * 64 + c];
    g = 0.5f * g * (1.f + erff(g * 0.70710678118654752f));  // exact gelu
    offy += pw_w[num * 128 + c] * g;
    offx += pw_w[num * 128 + 64 + c] * g;
  }
  float ref_y = (0.5f + (float)oy) * (2.f / 15.f) - 1.f;
  float ref_x = (0.5f + (float)ox) * (2.f / 15.f) - 1.f;
  float py = fminf(fmaxf(offy + ref_y, -1.f), 1.f);
  float px = fminf(fmaxf(offx + ref_x, -1.f), 1.f);
  pos_buf[(wg * 256 + n) * 2 + 0] = py;
  pos_buf[(wg * 256 + n) * 2 + 1] = px;
}

// ------------- bilinear sample kv (align_corners=True) -> xs[num][b][c][n]
__global__ __launch_bounds__(256) void k_sample(
    const float* __restrict__ x0, const float* __restrict__ x1,
    const float* __restrict__ pos_buf, float* __restrict__ xs_buf) {
  int wg = blockIdx.x;
  int cg = wg & 7;
  int b = (wg >> 3) & 7;
  int num = wg >> 6;
  const float* xj = (num == 2) ? x1 : x0;       // kv source: x0,x0,x1
  int n = threadIdx.x;
  int nb = num * 8 + b;
  float py = pos_buf[(nb * 256 + n) * 2 + 0];
  float px = pos_buf[(nb * 256 + n) * 2 + 1];
  float fy = (py + 1.f) * 31.5f;
  float fx = (px + 1.f) * 31.5f;
  float y0f = floorf(fy), x0f = floorf(fx);
  float wy = fy - y0f, wx = fx - x0f;
  int y0 = (int)y0f, xi0 = (int)x0f;
  int y1 = min(y0 + 1, 63), xi1 = min(xi0 + 1, 63);  // OOB tap has weight 0
  float w00 = (1.f - wy) * (1.f - wx), w01 = (1.f - wy) * wx;
  float w10 = wy * (1.f - wx), w11 = wy * wx;
  const float* xb = xj + b * 524288;
#pragma unroll
  for (int cc = 0; cc < 8; ++cc) {
    int c = cg * 8 + cc;
    const float* p = xb + c * 4096;
    float v = w00 * p[y0 * 64 + xi0] + w01 * p[y0 * 64 + xi1] +
              w10 * p[y1 * 64 + xi0] + w11 * p[y1 * 64 + xi1];
    xs_buf[(nb * 64 + c) * 256 + n] = v;
  }
}

// -------------------------------- k = pk_w@xs + pk_b ; v = pv_w@xs + pv_b
// grid 192 = nb(24) * which(2) * og(4); 16 outs each
__global__ __launch_bounds__(256) void k_kv(
    const float* __restrict__ xs_buf, const float* __restrict__ pk_w,
    const float* __restrict__ pk_b, const float* __restrict__ pv_w,
    const float* __restrict__ pv_b, float* __restrict__ k_buf,
    float* __restrict__ v_buf) {
  int wg = blockIdx.x;
  int og = wg & 3;
  int which = (wg >> 2) & 1;
  int nb = wg >> 3;
  int num = nb >> 3;
  int o0 = og * 16;
  const float* w = (which ? pv_w : pk_w) + num * 4096;
  const float* bias = (which ? pv_b : pk_b) + num * 64;
  float* ob = (which ? v_buf : k_buf) + nb * 16384;
  const float* xsb = xs_buf + nb * 16384;
  int n = threadIdx.x;
  float acc[16];
#pragma unroll
  for (int o = 0; o < 16; ++o) acc[o] = 0.f;
  for (int c = 0; c < 64; ++c) {
    float xv = xsb[c * 256 + n];
#pragma unroll
    for (int o = 0; o < 16; ++o) acc[o] += w[(o0 + o) * 64 + c] * xv;
  }
#pragma unroll
  for (int o = 0; o < 16; ++o) ob[(o0 + o) * 256 + n] = acc[o] + bias[o0 + o];
}

// ----------------- MFMA attention with LDS-staged bias table.
// S^T = K_A . Q_B (16x16x16 f16); C-layout of S^T == B-frag layout for PV.
// WG covers 256 consecutive m -> 4 query rows; wave w owns row mblock*4+w.
// Table rows rlo..rlo+67 staged as vertical half2 pairs, pitch 129.
__global__ __launch_bounds__(256, 4) void k_attn(
    float* __restrict__ q_buf, const float* __restrict__ k_buf,
    const float* __restrict__ v_buf, const float* __restrict__ pos_buf,
    const float* __restrict__ rpe) {
  int wg = blockIdx.x;
  int mblock = wg & 15;
  int h = (wg >> 4) & 3;
  int b = (wg >> 6) & 7;
  int num = wg >> 9;
  int nb = num * 8 + b;
  int tid = threadIdx.x;
  int lane = tid & 63;
  int wave = __builtin_amdgcn_readfirstlane(tid >> 6);
  int l15 = lane & 15;
  int quad = lane >> 4;

  __shared__ uint sT[67 * 129];     // (T[r][c], T[r+1][c]) as half2
  __shared__ uint s_kp[256 * 2];    // per key: [iy*129+ix, half2(fy,fx)]

  {
    float py = pos_buf[(nb * 256 + tid) * 2 + 0];
    float px = pos_buf[(nb * 256 + tid) * 2 + 1];
    float by = 31.5f * (1.f - py);
    float bx = 31.5f * (1.f - px);
    float iyf = floorf(by), ixf = floorf(bx);
    union { uint u; h2v hv; } cv;
    cv.hv.x = (_Float16)(by - iyf);
    cv.hv.y = (_Float16)(bx - ixf);
    s_kp[tid * 2] = (uint)((int)iyf * 129 + (int)ixf);
    s_kp[tid * 2 + 1] = cv.u;
  }
  const float* T = rpe + (num * 4 + h) * 16129;  // 127x127 raw table
  int rlo = mblock * 4;
  for (int i = tid; i < 67 * 128; i += 256) {
    int r = i >> 7, c = i & 127;
    int r0 = min(rlo + r, 126);
    int r1 = min(rlo + r + 1, 126);
    int cc = min(c, 126);
    union { uint u; h2v hv; } cv;
    cv.hv.x = (_Float16)T[r0 * 127 + cc];
    cv.hv.y = (_Float16)T[r1 * 127 + cc];
    sT[r * 129 + c] = cv.u;
  }
  __syncthreads();

  int hc = nb * 64 + h * 16;
  const float* kb = k_buf + hc * 256;
  const float* vb = v_buf + hc * 256;
  float* qb = q_buf + hc * 4096;

  // K frags: A[n][c]: n = l15 + 16t, c = quad*4+j
  // V frags: A[c][n]: c = l15, n = 16t + quad*4+j
  f16x4 kf[16], vf[16];
#pragma unroll
  for (int t = 0; t < 16; ++t) {
    int n = t * 16 + l15;
#pragma unroll
    for (int j = 0; j < 4; ++j)
      kf[t][j] = (_Float16)kb[(quad * 4 + j) * 256 + n];
    float4 vv = *(const float4*)(vb + l15 * 256 + t * 16 + quad * 4);
    vf[t][0] = (_Float16)vv.x; vf[t][1] = (_Float16)vv.y;
    vf[t][2] = (_Float16)vv.z; vf[t][3] = (_Float16)vv.w;
  }

#pragma unroll 1
  for (int mt = 0; mt < 4; ++mt) {
    int m = mblock * 256 + wave * 64 + mt * 16 + l15;
    int boff = wave * 129 + mt * 16 + l15;   // local pair-row=wave, col=mx
    f16x4 qf;
#pragma unroll
    for (int j = 0; j < 4; ++j)
      qf[j] = (_Float16)qb[(quad * 4 + j) * 4096 + m];

    f32x4 O = {0.f, 0.f, 0.f, 0.f};
    float L = 0.f;
#pragma unroll 4
    for (int t = 0; t < 16; ++t) {
      f32x4 Z = {0.f, 0.f, 0.f, 0.f};
      f32x4 S = __builtin_amdgcn_mfma_f32_16x16x16f16(kf[t], qf, Z, 0, 0, 0);
      f16x4 pf;
#pragma unroll
      for (int r = 0; r < 4; ++r) {
        int key = t * 16 + quad * 4 + r;
        int combo = (int)s_kp[key * 2];
        union { uint u; h2v hv; } fcv;
        fcv.u = s_kp[key * 2 + 1];
        int v = combo + boff;
        union { uint u; h2v hv; } d0, d1;
        d0.u = sT[v];
        d1.u = sT[v + 1];
        float fy = (float)fcv.hv.x, fx = (float)fcv.hv.y;
        float t00 = (float)d0.hv.x, t10 = (float)d0.hv.y;
        float t01 = (float)d1.hv.x, t11 = (float)d1.hv.y;
        float lx0 = fmaf(fx, t01 - t00, t00);
        float lx1 = fmaf(fx, t11 - t10, t10);
        float bias = fmaf(fy, lx1 - lx0, lx0);
        float s = fminf(fmaf(S[r], 0.25f, bias), 10.f);
        float e = __expf(s);
        L += e;
        pf[r] = (_Float16)e;
      }
      O = __builtin_amdgcn_mfma_f32_16x16x16f16(vf[t], pf, O, 0, 0, 0);
    }
    L += __shfl_xor(L, 16);
    L += __shfl_xor(L, 32);
    float rinv = 1.f / L;
#pragma unroll
    for (int r = 0; r < 4; ++r)
      qb[(quad * 4 + r) * 4096 + m] = O[r] * rinv;  // in-place over q
  }
}

// ---- po conv fused with residual: out[l][b][64+o] = x_l[..] + sum_num conv
// grid 512 = lv(2) * b(8) * tile(32 of 128 pos). No atomics.
__global__ __launch_bounds__(256) void k_po(
    const float* __restrict__ attn_buf, const float* __restrict__ x1,
    const float* __restrict__ x2, const float* __restrict__ po_w,
    const float* __restrict__ po_b, float* __restrict__ out) {
  int wg = blockIdx.x;
  int tile = wg & 31;
  int b = (wg >> 5) & 7;
  int lv = wg >> 8;                 // 0 -> level1 (num0), 1 -> level2 (num1+2)
  int p0 = tile * 128;
  int tid = threadIdx.x;
  int lane = tid & 63;
  int og = __builtin_amdgcn_readfirstlane(tid >> 6);
  int o0 = og * 16;
  const float* xsrc = (lv == 0) ? x1 : x2;
  float acc[2][16];
#pragma unroll
  for (int i = 0; i < 16; ++i) {
    int o = o0 + i;
    float2 xv = *(const float2*)(xsrc + b * 524288 + (64 + o) * 4096 + p0 +
                                 lane * 2);
    float bsum = (lv == 0) ? po_b[o] : (po_b[64 + o] + po_b[128 + o]);
    acc[0][i] = xv.x + bsum;
    acc[1][i] = xv.y + bsum;
  }
  __shared__ float lx[16 * 128];
  int numA = (lv == 0) ? 0 : 1;
  int numB = (lv == 0) ? 0 : 2;
  for (int num = numA; num <= numB; ++num) {
    const float* abase = attn_buf + (num * 8 + b) * 262144;
    const float* w = po_w + num * 4096;
    for (int cc = 0; cc < 64; cc += 16) {
      __syncthreads();
#pragma unroll
      for (int r = 0; r < 2; ++r) {
        int idx = tid + r * 256;
        int c = idx >> 5, col4 = idx & 31;
        *(float4*)(lx + c * 128 + col4 * 4) =
            *(const float4*)(abase + (cc + c) * 4096 + p0 + col4 * 4);
      }
      __syncthreads();
#pragma unroll
      for (int c = 0; c < 16; ++c) {
        float2 xv = *(const float2*)(lx + c * 128 + lane * 2);
#pragma unroll
        for (int i = 0; i < 16; ++i) {
          float wv = w[(o0 + i) * 64 + cc + c];
          acc[0][i] += xv.x * wv;
          acc[1][i] += xv.y * wv;
        }
      }
    }
  }
  float* ob = out + ((lv + 1) * 8 + b) * 524288 + 64 * 4096;
#pragma unroll
  for (int i = 0; i < 16; ++i) {
    int o = o0 + i;
    float2 r2 = {acc[0][i], acc[1][i]};
    *(float2*)(ob + o * 4096 + p0 + lane * 2) = r2;
  }
}

extern "C" void kernel_launch(void* const* d_in, const int* in_sizes, int n_in,
                              void* d_out, int out_size, void* d_ws,
                              size_t ws_size, hipStream_t stream) {
  const float* x0 = (const float*)d_in[0];
  const float* x1 = (const float*)d_in[1];
  const float* x2 = (const float*)d_in[2];
  const float* pq_w = (const float*)d_in[3];
  const float* pq_b = (const float*)d_in[4];
  const float* dw_w = (const float*)d_in[5];
  const float* dw_b = (const float*)d_in[6];
  const float* ln_g = (const float*)d_in[7];
  const float* ln_b = (const float*)d_in[8];
  const float* pw_w = (const float*)d_in[9];
  const float* pk_w = (const float*)d_in[10];
  const float* pk_b = (const float*)d_in[11];
  const float* pv_w = (const float*)d_in[12];
  const float* pv_b = (const float*)d_in[13];
  const float* po_w = (const float*)d_in[14];
  const float* po_b = (const float*)d_in[15];
  const float* rpe = (const float*)d_in[16];
  float* out = (float*)d_out;
  float* ws = (float*)d_ws;

  // ws layout (floats): q/attn (in-place) 6291456, pos 12288, xs 393216,
  // k 393216, v 393216 -> 29,933,568 bytes (round-0-proven size).
  float* q_buf = ws;
  float* pos_buf = q_buf + 6291456;
  float* xs_buf = pos_buf + 12288;
  float* k_buf = xs_buf + 393216;
  float* v_buf = k_buf + 393216;

  hipLaunchKernelGGL(k_copy, dim3(8192), dim3(256), 0, stream, x0, x1, x2, out);
  hipLaunchKernelGGL(k_qconv, dim3(768), dim3(256), 0, stream, x1, x2, pq_w,
                     pq_b, q_buf);
  hipLaunchKernelGGL(k_offset, dim3(24), dim3(256), 0, stream, q_buf, dw_w,
                     dw_b, ln_g, ln_b, pw_w, pos_buf);
  hipLaunchKernelGGL(k_sample, dim3(192), dim3(256), 0, stream, x0, x1,
                     pos_buf, xs_buf);
  hipLaunchKernelGGL(k_kv, dim3(192), dim3(256), 0, stream, xs_buf, pk_w, pk_b,
                     pv_w, pv_b, k_buf, v_buf);
  hipLaunchKernelGGL(k_attn, dim3(1536), dim3(256), 0, stream, q_buf, k_buf,
                     v_buf, pos_buf, rpe);
  hipLaunchKernelGGL(k_po, dim3(512), dim3(256), 0, stream, q_buf, x1, x2,
                     po_w, po_b, out);
}

// Round 5
// 1363.210 us; speedup vs baseline: 19.5607x; 19.5607x over previous
//
#include <hip/hip_runtime.h>
#include <math.h>

// Problem constants: B=8, C=128, H=W=64, NC=64, NH=4, HC=16, KS=4,
// Hk=Wk=16, Ns=256, HW=4096, NB=3 blocks: (i,j) = (1,0),(2,0),(2,1)

typedef _Float16 f16x4 __attribute__((ext_vector_type(4)));
typedef float f32x4 __attribute__((ext_vector_type(4)));
typedef _Float16 h2v __attribute__((ext_vector_type(2)));

// ---- copy: level0 full + level1/2 channels 0..63 (64..127 written by k_po)
__global__ __launch_bounds__(256) void k_copy(
    const float* __restrict__ x0, const float* __restrict__ x1,
    const float* __restrict__ x2, float* __restrict__ out) {
  int i = blockIdx.x * 256 + threadIdx.x;       // f4 idx, total 2097152
  const float4* x0f = (const float4*)x0;
  const float4* x1f = (const float4*)x1;
  const float4* x2f = (const float4*)x2;
  float4 v;
  int oidx;
  if (i < 1048576) {
    oidx = i;
    v = x0f[i];
  } else {
    int j = i - 1048576;
    int half = j >> 19;          // 0 -> level1, 1 -> level2
    int r = j & 524287;
    int bb = r >> 16;
    int off = r & 65535;         // f4 within b's c<64 block
    v = (half == 0) ? x1f[bb * 131072 + off] : x2f[bb * 131072 + off];
    oidx = ((half + 1) * 8 + bb) * 131072 + off;
  }
  ((float4*)out)[oidx] = v;
}

// ------------------------------------------------- q = pq_w @ x_i[:, :64] + b
// grid 768 = 3 num * 8 b * 32 tiles(128 pos); 256 thr: 2 pos x 16 out each
__global__ __launch_bounds__(256) void k_qconv(
    const float* __restrict__ x1, const float* __restrict__ x2,
    const float* __restrict__ pq_w, const float* __restrict__ pq_b,
    float* __restrict__ q_buf) {
  int wg = blockIdx.x;
  int tile = wg & 31;
  int b = (wg >> 5) & 7;
  int num = wg >> 8;
  const float* xin = (num == 0) ? x1 : x2;
  const float* xbase = xin + b * 524288;
  const float* w = pq_w + num * 4096;
  int p0 = tile * 128;
  int tid = threadIdx.x;
  int lane = tid & 63;
  int og = __builtin_amdgcn_readfirstlane(tid >> 6);
  int o0 = og * 16;
  __shared__ float lx[16 * 128];
  float acc[2][16];
#pragma unroll
  for (int j = 0; j < 2; ++j)
#pragma unroll
    for (int i = 0; i < 16; ++i) acc[j][i] = 0.f;
  for (int cc = 0; cc < 64; cc += 16) {
    __syncthreads();
#pragma unroll
    for (int r = 0; r < 2; ++r) {
      int idx = tid + r * 256;                 // 512 f4 = 16 rows x 32 f4
      int c = idx >> 5, col4 = idx & 31;
      *(float4*)(lx + c * 128 + col4 * 4) =
          *(const float4*)(xbase + (cc + c) * 4096 + p0 + col4 * 4);
    }
    __syncthreads();
#pragma unroll
    for (int c = 0; c < 16; ++c) {
      float2 xv = *(const float2*)(lx + c * 128 + lane * 2);
#pragma unroll
      for (int i = 0; i < 16; ++i) {
        float wv = w[(o0 + i) * 64 + cc + c];  // uniform -> s_load
        acc[0][i] += xv.x * wv;
        acc[1][i] += xv.y * wv;
      }
    }
  }
  float* qb = q_buf + (num * 8 + b) * 262144;
#pragma unroll
  for (int i = 0; i < 16; ++i) {
    int o = o0 + i;
    float bias = pq_b[num * 64 + o];
    float2 r2 = {acc[0][i] + bias, acc[1][i] + bias};
    *(float2*)(qb + o * 4096 + p0 + lane * 2) = r2;
  }
}

// ---------------- offset head: depthwise 4x4 s4 + LN + GELU + proj -> pos
__global__ __launch_bounds__(256) void k_offset(
    const float* __restrict__ q_buf, const float* __restrict__ dw_w,
    const float* __restrict__ dw_b, const float* __restrict__ ln_g,
    const float* __restrict__ ln_b, const float* __restrict__ pw_w,
    float* __restrict__ pos_buf) {
  int wg = blockIdx.x;
  int num = wg >> 3;
  int n = threadIdx.x;
  int oy = n >> 4, ox = n & 15;
  const float* qb = q_buf + wg * 262144;
  float off[64];
  float sum = 0.f, sumsq = 0.f;
#pragma unroll
  for (int c = 0; c < 64; ++c) {
    const float* wp = dw_w + (num * 64 + c) * 16;
    const float* qp = qb + c * 4096 + oy * 256 + ox * 4;
    float4 r0 = *(const float4*)(qp);
    float4 r1 = *(const float4*)(qp + 64);
    float4 r2 = *(const float4*)(qp + 128);
    float4 r3 = *(const float4*)(qp + 192);
    float s = dw_b[num * 64 + c];
    s += wp[0] * r0.x + wp[1] * r0.y + wp[2] * r0.z + wp[3] * r0.w;
    s += wp[4] * r1.x + wp[5] * r1.y + wp[6] * r1.z + wp[7] * r1.w;
    s += wp[8] * r2.x + wp[9] * r2.y + wp[10] * r2.z + wp[11] * r2.w;
    s += wp[12] * r3.x + wp[13] * r3.y + wp[14] * r3.z + wp[15] * r3.w;
    off[c] = s;
    sum += s;
    sumsq += s * s;
  }
  float mu = sum * 0.015625f;
  float var = sumsq * 0.015625f - mu * mu;
  float rstd = rsqrtf(var + 1e-5f);
  float offy = 0.f, offx = 0.f;
#pragma unroll
  for (int c = 0; c < 64; ++c) {
    float g = (off[c] - mu) * rstd * ln_g[num * 64 + c] + ln_b[num * 64 + c];
    g = 0.5f * g * (1.f + erff(g * 0.70710678118654752f));  // exact gelu
    offy += pw_w[num * 128 + c] * g;
    offx += pw_w[num * 128 + 64 + c] * g;
  }
  float ref_y = (0.5f + (float)oy) * (2.f / 15.f) - 1.f;
  float ref_x = (0.5f + (float)ox) * (2.f / 15.f) - 1.f;
  float py = fminf(fmaxf(offy + ref_y, -1.f), 1.f);
  float px = fminf(fmaxf(offx + ref_x, -1.f), 1.f);
  pos_buf[(wg * 256 + n) * 2 + 0] = py;
  pos_buf[(wg * 256 + n) * 2 + 1] = px;
}

// ------------- bilinear sample kv (align_corners=True) -> xs[num][b][c][n]
__global__ __launch_bounds__(256) void k_sample(
    const float* __restrict__ x0, const float* __restrict__ x1,
    const float* __restrict__ pos_buf, float* __restrict__ xs_buf) {
  int wg = blockIdx.x;
  int cg = wg & 7;
  int b = (wg >> 3) & 7;
  int num = wg >> 6;
  const float* xj = (num == 2) ? x1 : x0;       // kv source: x0,x0,x1
  int n = threadIdx.x;
  int nb = num * 8 + b;
  float py = pos_buf[(nb * 256 + n) * 2 + 0];
  float px = pos_buf[(nb * 256 + n) * 2 + 1];
  float fy = (py + 1.f) * 31.5f;
  float fx = (px + 1.f) * 31.5f;
  float y0f = floorf(fy), x0f = floorf(fx);
  float wy = fy - y0f, wx = fx - x0f;
  int y0 = (int)y0f, xi0 = (int)x0f;
  int y1 = min(y0 + 1, 63), xi1 = min(xi0 + 1, 63);  // OOB tap has weight 0
  float w00 = (1.f - wy) * (1.f - wx), w01 = (1.f - wy) * wx;
  float w10 = wy * (1.f - wx), w11 = wy * wx;
  const float* xb = xj + b * 524288;
#pragma unroll
  for (int cc = 0; cc < 8; ++cc) {
    int c = cg * 8 + cc;
    const float* p = xb + c * 4096;
    float v = w00 * p[y0 * 64 + xi0] + w01 * p[y0 * 64 + xi1] +
              w10 * p[y1 * 64 + xi0] + w11 * p[y1 * 64 + xi1];
    xs_buf[(nb * 64 + c) * 256 + n] = v;
  }
}

// -------------------------------- k = pk_w@xs + pk_b ; v = pv_w@xs + pv_b
// grid 192 = nb(24) * which(2) * og(4); 16 outs each
__global__ __launch_bounds__(256) void k_kv(
    const float* __restrict__ xs_buf, const float* __restrict__ pk_w,
    const float* __restrict__ pk_b, const float* __restrict__ pv_w,
    const float* __restrict__ pv_b, float* __restrict__ k_buf,
    float* __restrict__ v_buf) {
  int wg = blockIdx.x;
  int og = wg & 3;
  int which = (wg >> 2) & 1;
  int nb = wg >> 3;
  int num = nb >> 3;
  int o0 = og * 16;
  const float* w = (which ? pv_w : pk_w) + num * 4096;
  const float* bias = (which ? pv_b : pk_b) + num * 64;
  float* ob = (which ? v_buf : k_buf) + nb * 16384;
  const float* xsb = xs_buf + nb * 16384;
  int n = threadIdx.x;
  float acc[16];
#pragma unroll
  for (int o = 0; o < 16; ++o) acc[o] = 0.f;
  for (int c = 0; c < 64; ++c) {
    float xv = xsb[c * 256 + n];
#pragma unroll
    for (int o = 0; o < 16; ++o) acc[o] += w[(o0 + o) * 64 + c] * xv;
  }
#pragma unroll
  for (int o = 0; o < 16; ++o) ob[(o0 + o) * 256 + n] = acc[o] + bias[o0 + o];
}

// ----------------- MFMA attention with LDS-staged bias table.
// S^T = K_A . Q_B (16x16x16 f16); C-layout of S^T == B-frag layout for PV.
// WG covers 256 consecutive m -> 4 query rows; wave w owns row mblock*4+w.
// Table rows rlo..rlo+67 staged as vertical half2 pairs, pitch 129.
// __launch_bounds__(256,2): cap 256 VGPR. (256,4) forced 64 VGPR -> scratch
// spill -> 72 GB HBM traffic/dispatch, 26 ms (round-4 lesson). Never cap
// below live state (kf+vf alone = 64 VGPRs).
__global__ __launch_bounds__(256, 2) void k_attn(
    float* __restrict__ q_buf, const float* __restrict__ k_buf,
    const float* __restrict__ v_buf, const float* __restrict__ pos_buf,
    const float* __restrict__ rpe) {
  int wg = blockIdx.x;
  int mblock = wg & 15;
  int h = (wg >> 4) & 3;
  int b = (wg >> 6) & 7;
  int num = wg >> 9;
  int nb = num * 8 + b;
  int tid = threadIdx.x;
  int lane = tid & 63;
  int wave = __builtin_amdgcn_readfirstlane(tid >> 6);
  int l15 = lane & 15;
  int quad = lane >> 4;

  __shared__ uint sT[67 * 129];     // (T[r][c], T[r+1][c]) as half2
  __shared__ uint2 s_kp[256];       // per key: [iy*129+ix, half2(fy,fx)]

  {
    float py = pos_buf[(nb * 256 + tid) * 2 + 0];
    float px = pos_buf[(nb * 256 + tid) * 2 + 1];
    float by = 31.5f * (1.f - py);
    float bx = 31.5f * (1.f - px);
    float iyf = floorf(by), ixf = floorf(bx);
    union { uint u; h2v hv; } cv;
    cv.hv.x = (_Float16)(by - iyf);
    cv.hv.y = (_Float16)(bx - ixf);
    uint2 kp;
    kp.x = (uint)((int)iyf * 129 + (int)ixf);
    kp.y = cv.u;
    s_kp[tid] = kp;
  }
  const float* T = rpe + (num * 4 + h) * 16129;  // 127x127 raw table
  int rlo = mblock * 4;
  for (int i = tid; i < 67 * 128; i += 256) {
    int r = i >> 7, c = i & 127;
    int r0 = min(rlo + r, 126);
    int r1 = min(rlo + r + 1, 126);
    int cc = min(c, 126);
    union { uint u; h2v hv; } cv;
    cv.hv.x = (_Float16)T[r0 * 127 + cc];
    cv.hv.y = (_Float16)T[r1 * 127 + cc];
    sT[r * 129 + c] = cv.u;
  }
  __syncthreads();

  int hc = nb * 64 + h * 16;
  const float* kb = k_buf + hc * 256;
  const float* vb = v_buf + hc * 256;
  float* qb = q_buf + hc * 4096;

  // K frags: A[n][c]: n = l15 + 16t, c = quad*4+j
  // V frags: A[c][n]: c = l15, n = 16t + quad*4+j
  f16x4 kf[16], vf[16];
#pragma unroll
  for (int t = 0; t < 16; ++t) {
    int n = t * 16 + l15;
#pragma unroll
    for (int j = 0; j < 4; ++j)
      kf[t][j] = (_Float16)kb[(quad * 4 + j) * 256 + n];
    float4 vv = *(const float4*)(vb + l15 * 256 + t * 16 + quad * 4);
    vf[t][0] = (_Float16)vv.x; vf[t][1] = (_Float16)vv.y;
    vf[t][2] = (_Float16)vv.z; vf[t][3] = (_Float16)vv.w;
  }

#pragma unroll 1
  for (int mt = 0; mt < 4; ++mt) {
    int m = mblock * 256 + wave * 64 + mt * 16 + l15;
    int boff = wave * 129 + mt * 16 + l15;   // local pair-row=wave, col=mx
    f16x4 qf;
#pragma unroll
    for (int j = 0; j < 4; ++j)
      qf[j] = (_Float16)qb[(quad * 4 + j) * 4096 + m];

    f32x4 O = {0.f, 0.f, 0.f, 0.f};
    float L = 0.f;
#pragma unroll 4
    for (int t = 0; t < 16; ++t) {
      f32x4 Z = {0.f, 0.f, 0.f, 0.f};
      f32x4 S = __builtin_amdgcn_mfma_f32_16x16x16f16(kf[t], qf, Z, 0, 0, 0);
      f16x4 pf;
#pragma unroll
      for (int r = 0; r < 4; ++r) {
        int key = t * 16 + quad * 4 + r;
        uint2 kp = s_kp[key];
        union { uint u; h2v hv; } fcv;
        fcv.u = kp.y;
        int v = (int)kp.x + boff;
        union { uint u; h2v hv; } d0, d1;
        d0.u = sT[v];
        d1.u = sT[v + 1];
        float fy = (float)fcv.hv.x, fx = (float)fcv.hv.y;
        float t00 = (float)d0.hv.x, t10 = (float)d0.hv.y;
        float t01 = (float)d1.hv.x, t11 = (float)d1.hv.y;
        float lx0 = fmaf(fx, t01 - t00, t00);
        float lx1 = fmaf(fx, t11 - t10, t10);
        float bias = fmaf(fy, lx1 - lx0, lx0);
        float s = fminf(fmaf(S[r], 0.25f, bias), 10.f);
        float e = __expf(s);
        L += e;
        pf[r] = (_Float16)e;
      }
      O = __builtin_amdgcn_mfma_f32_16x16x16f16(vf[t], pf, O, 0, 0, 0);
    }
    L += __shfl_xor(L, 16);
    L += __shfl_xor(L, 32);
    float rinv = 1.f / L;
#pragma unroll
    for (int r = 0; r < 4; ++r)
      qb[(quad * 4 + r) * 4096 + m] = O[r] * rinv;  // in-place over q
  }
}

// ---- po conv fused with residual: out[l][b][64+o] = x_l[..] + sum_num conv
// grid 512 = lv(2) * b(8) * tile(32 of 128 pos). No atomics.
__global__ __launch_bounds__(256) void k_po(
    const float* __restrict__ attn_buf, const float* __restrict__ x1,
    const float* __restrict__ x2, const float* __restrict__ po_w,
    const float* __restrict__ po_b, float* __restrict__ out) {
  int wg = blockIdx.x;
  int tile = wg & 31;
  int b = (wg >> 5) & 7;
  int lv = wg >> 8;                 // 0 -> level1 (num0), 1 -> level2 (num1+2)
  int p0 = tile * 128;
  int tid = threadIdx.x;
  int lane = tid & 63;
  int og = __builtin_amdgcn_readfirstlane(tid >> 6);
  int o0 = og * 16;
  const float* xsrc = (lv == 0) ? x1 : x2;
  float acc[2][16];
#pragma unroll
  for (int i = 0; i < 16; ++i) {
    int o = o0 + i;
    float2 xv = *(const float2*)(xsrc + b * 524288 + (64 + o) * 4096 + p0 +
                                 lane * 2);
    float bsum = (lv == 0) ? po_b[o] : (po_b[64 + o] + po_b[128 + o]);
    acc[0][i] = xv.x + bsum;
    acc[1][i] = xv.y + bsum;
  }
  __shared__ float lx[16 * 128];
  int numA = (lv == 0) ? 0 : 1;
  int numB = (lv == 0) ? 0 : 2;
  for (int num = numA; num <= numB; ++num) {
    const float* abase = attn_buf + (num * 8 + b) * 262144;
    const float* w = po_w + num * 4096;
    for (int cc = 0; cc < 64; cc += 16) {
      __syncthreads();
#pragma unroll
      for (int r = 0; r < 2; ++r) {
        int idx = tid + r * 256;
        int c = idx >> 5, col4 = idx & 31;
        *(float4*)(lx + c * 128 + col4 * 4) =
            *(const float4*)(abase + (cc + c) * 4096 + p0 + col4 * 4);
      }
      __syncthreads();
#pragma unroll
      for (int c = 0; c < 16; ++c) {
        float2 xv = *(const float2*)(lx + c * 128 + lane * 2);
#pragma unroll
        for (int i = 0; i < 16; ++i) {
          float wv = w[(o0 + i) * 64 + cc + c];
          acc[0][i] += xv.x * wv;
          acc[1][i] += xv.y * wv;
        }
      }
    }
  }
  float* ob = out + ((lv + 1) * 8 + b) * 524288 + 64 * 4096;
#pragma unroll
  for (int i = 0; i < 16; ++i) {
    int o = o0 + i;
    float2 r2 = {acc[0][i], acc[1][i]};
    *(float2*)(ob + o * 4096 + p0 + lane * 2) = r2;
  }
}

extern "C" void kernel_launch(void* const* d_in, const int* in_sizes, int n_in,
                              void* d_out, int out_size, void* d_ws,
                              size_t ws_size, hipStream_t stream) {
  const float* x0 = (const float*)d_in[0];
  const float* x1 = (const float*)d_in[1];
  const float* x2 = (const float*)d_in[2];
  const float* pq_w = (const float*)d_in[3];
  const float* pq_b = (const float*)d_in[4];
  const float* dw_w = (const float*)d_in[5];
  const float* dw_b = (const float*)d_in[6];
  const float* ln_g = (const float*)d_in[7];
  const float* ln_b = (const float*)d_in[8];
  const float* pw_w = (const float*)d_in[9];
  const float* pk_w = (const float*)d_in[10];
  const float* pk_b = (const float*)d_in[11];
  const float* pv_w = (const float*)d_in[12];
  const float* pv_b = (const float*)d_in[13];
  const float* po_w = (const float*)d_in[14];
  const float* po_b = (const float*)d_in[15];
  const float* rpe = (const float*)d_in[16];
  float* out = (float*)d_out;
  float* ws = (float*)d_ws;

  // ws layout (floats): q/attn (in-place) 6291456, pos 12288, xs 393216,
  // k 393216, v 393216 -> 29,933,568 bytes (round-0-proven size).
  float* q_buf = ws;
  float* pos_buf = q_buf + 6291456;
  float* xs_buf = pos_buf + 12288;
  float* k_buf = xs_buf + 393216;
  float* v_buf = k_buf + 393216;

  hipLaunchKernelGGL(k_copy, dim3(8192), dim3(256), 0, stream, x0, x1, x2, out);
  hipLaunchKernelGGL(k_qconv, dim3(768), dim3(256), 0, stream, x1, x2, pq_w,
                     pq_b, q_buf);
  hipLaunchKernelGGL(k_offset, dim3(24), dim3(256), 0, stream, q_buf, dw_w,
                     dw_b, ln_g, ln_b, pw_w, pos_buf);
  hipLaunchKernelGGL(k_sample, dim3(192), dim3(256), 0, stream, x0, x1,
                     pos_buf, xs_buf);
  hipLaunchKernelGGL(k_kv, dim3(192), dim3(256), 0, stream, xs_buf, pk_w, pk_b,
                     pv_w, pv_b, k_buf, v_buf);
  hipLaunchKernelGGL(k_attn, dim3(1536), dim3(256), 0, stream, q_buf, k_buf,
                     v_buf, pos_buf, rpe);
  hipLaunchKernelGGL(k_po, dim3(512), dim3(256), 0, stream, q_buf, x1, x2,
                     po_w, po_b, out);
}

// Round 6
// 683.451 us; speedup vs baseline: 39.0157x; 1.9946x over previous
//
#include <hip/hip_runtime.h>
#include <hip/hip_fp16.h>
#include <math.h>

// Problem constants: B=8, C=128, H=W=64, NC=64, NH=4, HC=16, KS=4,
// Hk=Wk=16, Ns=256, HW=4096, NB=3 blocks: (i,j) = (1,0),(2,0),(2,1)

typedef _Float16 f16x4 __attribute__((ext_vector_type(4)));
typedef float f32x4 __attribute__((ext_vector_type(4)));

// ---- copy: level0 full + level1/2 channels 0..63 (64..127 written by k_po)
__global__ __launch_bounds__(256) void k_copy(
    const float* __restrict__ x0, const float* __restrict__ x1,
    const float* __restrict__ x2, float* __restrict__ out) {
  int i = blockIdx.x * 256 + threadIdx.x;       // f4 idx, total 2097152
  const float4* x0f = (const float4*)x0;
  const float4* x1f = (const float4*)x1;
  const float4* x2f = (const float4*)x2;
  float4 v;
  int oidx;
  if (i < 1048576) {
    oidx = i;
    v = x0f[i];
  } else {
    int j = i - 1048576;
    int half = j >> 19;          // 0 -> level1, 1 -> level2
    int r = j & 524287;
    int bb = r >> 16;
    int off = r & 65535;         // f4 within b's c<64 block
    v = (half == 0) ? x1f[bb * 131072 + off] : x2f[bb * 131072 + off];
    oidx = ((half + 1) * 8 + bb) * 131072 + off;
  }
  ((float4*)out)[oidx] = v;
}

// ------------------------------------------------- q = pq_w @ x_i[:, :64] + b
// grid 768 = 3 num * 8 b * 32 tiles(128 pos); 256 thr: 2 pos x 16 out each
__global__ __launch_bounds__(256) void k_qconv(
    const float* __restrict__ x1, const float* __restrict__ x2,
    const float* __restrict__ pq_w, const float* __restrict__ pq_b,
    float* __restrict__ q_buf) {
  int wg = blockIdx.x;
  int tile = wg & 31;
  int b = (wg >> 5) & 7;
  int num = wg >> 8;
  const float* xin = (num == 0) ? x1 : x2;
  const float* xbase = xin + b * 524288;
  const float* w = pq_w + num * 4096;
  int p0 = tile * 128;
  int tid = threadIdx.x;
  int lane = tid & 63;
  int og = __builtin_amdgcn_readfirstlane(tid >> 6);
  int o0 = og * 16;
  __shared__ float lx[16 * 128];
  float acc[2][16];
#pragma unroll
  for (int j = 0; j < 2; ++j)
#pragma unroll
    for (int i = 0; i < 16; ++i) acc[j][i] = 0.f;
  for (int cc = 0; cc < 64; cc += 16) {
    __syncthreads();
#pragma unroll
    for (int r = 0; r < 2; ++r) {
      int idx = tid + r * 256;                 // 512 f4 = 16 rows x 32 f4
      int c = idx >> 5, col4 = idx & 31;
      *(float4*)(lx + c * 128 + col4 * 4) =
          *(const float4*)(xbase + (cc + c) * 4096 + p0 + col4 * 4);
    }
    __syncthreads();
#pragma unroll
    for (int c = 0; c < 16; ++c) {
      float2 xv = *(const float2*)(lx + c * 128 + lane * 2);
#pragma unroll
      for (int i = 0; i < 16; ++i) {
        float wv = w[(o0 + i) * 64 + cc + c];  // uniform -> s_load
        acc[0][i] += xv.x * wv;
        acc[1][i] += xv.y * wv;
      }
    }
  }
  float* qb = q_buf + (num * 8 + b) * 262144;
#pragma unroll
  for (int i = 0; i < 16; ++i) {
    int o = o0 + i;
    float bias = pq_b[num * 64 + o];
    float2 r2 = {acc[0][i] + bias, acc[1][i] + bias};
    *(float2*)(qb + o * 4096 + p0 + lane * 2) = r2;
  }
}

// ---------------- offset head: depthwise 4x4 s4 + LN + GELU + proj -> pos
__global__ __launch_bounds__(256) void k_offset(
    const float* __restrict__ q_buf, const float* __restrict__ dw_w,
    const float* __restrict__ dw_b, const float* __restrict__ ln_g,
    const float* __restrict__ ln_b, const float* __restrict__ pw_w,
    float* __restrict__ pos_buf) {
  int wg = blockIdx.x;
  int num = wg >> 3;
  int n = threadIdx.x;
  int oy = n >> 4, ox = n & 15;
  const float* qb = q_buf + wg * 262144;
  float off[64];
  float sum = 0.f, sumsq = 0.f;
#pragma unroll
  for (int c = 0; c < 64; ++c) {
    const float* wp = dw_w + (num * 64 + c) * 16;
    const float* qp = qb + c * 4096 + oy * 256 + ox * 4;
    float4 r0 = *(const float4*)(qp);
    float4 r1 = *(const float4*)(qp + 64);
    float4 r2 = *(const float4*)(qp + 128);
    float4 r3 = *(const float4*)(qp + 192);
    float s = dw_b[num * 64 + c];
    s += wp[0] * r0.x + wp[1] * r0.y + wp[2] * r0.z + wp[3] * r0.w;
    s += wp[4] * r1.x + wp[5] * r1.y + wp[6] * r1.z + wp[7] * r1.w;
    s += wp[8] * r2.x + wp[9] * r2.y + wp[10] * r2.z + wp[11] * r2.w;
    s += wp[12] * r3.x + wp[13] * r3.y + wp[14] * r3.z + wp[15] * r3.w;
    off[c] = s;
    sum += s;
    sumsq += s * s;
  }
  float mu = sum * 0.015625f;
  float var = sumsq * 0.015625f - mu * mu;
  float rstd = rsqrtf(var + 1e-5f);
  float offy = 0.f, offx = 0.f;
#pragma unroll
  for (int c = 0; c < 64; ++c) {
    float g = (off[c] - mu) * rstd * ln_g[num * 64 + c] + ln_b[num * 64 + c];
    g = 0.5f * g * (1.f + erff(g * 0.70710678118654752f));  // exact gelu
    offy += pw_w[num * 128 + c] * g;
    offx += pw_w[num * 128 + 64 + c] * g;
  }
  float ref_y = (0.5f + (float)oy) * (2.f / 15.f) - 1.f;
  float ref_x = (0.5f + (float)ox) * (2.f / 15.f) - 1.f;
  float py = fminf(fmaxf(offy + ref_y, -1.f), 1.f);
  float px = fminf(fmaxf(offx + ref_x, -1.f), 1.f);
  pos_buf[(wg * 256 + n) * 2 + 0] = py;
  pos_buf[(wg * 256 + n) * 2 + 1] = px;
}

// ------------- bilinear sample kv (align_corners=True) -> xs[num][b][c][n]
__global__ __launch_bounds__(256) void k_sample(
    const float* __restrict__ x0, const float* __restrict__ x1,
    const float* __restrict__ pos_buf, float* __restrict__ xs_buf) {
  int wg = blockIdx.x;
  int cg = wg & 7;
  int b = (wg >> 3) & 7;
  int num = wg >> 6;
  const float* xj = (num == 2) ? x1 : x0;       // kv source: x0,x0,x1
  int n = threadIdx.x;
  int nb = num * 8 + b;
  float py = pos_buf[(nb * 256 + n) * 2 + 0];
  float px = pos_buf[(nb * 256 + n) * 2 + 1];
  float fy = (py + 1.f) * 31.5f;
  float fx = (px + 1.f) * 31.5f;
  float y0f = floorf(fy), x0f = floorf(fx);
  float wy = fy - y0f, wx = fx - x0f;
  int y0 = (int)y0f, xi0 = (int)x0f;
  int y1 = min(y0 + 1, 63), xi1 = min(xi0 + 1, 63);  // OOB tap has weight 0
  float w00 = (1.f - wy) * (1.f - wx), w01 = (1.f - wy) * wx;
  float w10 = wy * (1.f - wx), w11 = wy * wx;
  const float* xb = xj + b * 524288;
#pragma unroll
  for (int cc = 0; cc < 8; ++cc) {
    int c = cg * 8 + cc;
    const float* p = xb + c * 4096;
    float v = w00 * p[y0 * 64 + xi0] + w01 * p[y0 * 64 + xi1] +
              w10 * p[y1 * 64 + xi0] + w11 * p[y1 * 64 + xi1];
    xs_buf[(nb * 64 + c) * 256 + n] = v;
  }
}

// -------------------------------- k = pk_w@xs + pk_b ; v = pv_w@xs + pv_b
// grid 192 = nb(24) * which(2) * og(4); 16 outs each
__global__ __launch_bounds__(256) void k_kv(
    const float* __restrict__ xs_buf, const float* __restrict__ pk_w,
    const float* __restrict__ pk_b, const float* __restrict__ pv_w,
    const float* __restrict__ pv_b, float* __restrict__ k_buf,
    float* __restrict__ v_buf) {
  int wg = blockIdx.x;
  int og = wg & 3;
  int which = (wg >> 2) & 1;
  int nb = wg >> 3;
  int num = nb >> 3;
  int o0 = og * 16;
  const float* w = (which ? pv_w : pk_w) + num * 4096;
  const float* bias = (which ? pv_b : pk_b) + num * 64;
  float* ob = (which ? v_buf : k_buf) + nb * 16384;
  const float* xsb = xs_buf + nb * 16384;
  int n = threadIdx.x;
  float acc[16];
#pragma unroll
  for (int o = 0; o < 16; ++o) acc[o] = 0.f;
  for (int c = 0; c < 64; ++c) {
    float xv = xsb[c * 256 + n];
#pragma unroll
    for (int o = 0; o < 16; ++o) acc[o] += w[(o0 + o) * 64 + c] * xv;
  }
#pragma unroll
  for (int o = 0; o < 16; ++o) ob[(o0 + o) * 256 + n] = acc[o] + bias[o0 + o];
}

// -------- build paired-f16 bias table: tpad2[tbl][r][c] = half2(T[r][c],
// T[r][c+1]) with row/col clamped to 126 (clamped taps always have weight 0).
// 12 tables * 128*128 * 4B = 786 KB, ALIASED into dead xs_buf (run after k_kv;
// round-3-proven aliasing — do NOT grow ws past 29.93 MB, round-2 lesson).
__global__ __launch_bounds__(128) void k_padrpe(
    const float* __restrict__ rpe, __half2* __restrict__ tpad2) {
  int wg = blockIdx.x;              // 12 tables * 128 rows
  int tbl = wg >> 7;
  int r = wg & 127;
  int c = threadIdx.x;
  int rs = min(r, 126);
  int c0 = min(c, 126), c1 = min(c + 1, 126);
  const float* T = rpe + tbl * 16129;
  tpad2[tbl * 16384 + r * 128 + c] =
      __floats2half2_rn(T[rs * 127 + c0], T[rs * 127 + c1]);
}

// ----------------- MFMA attention. S^T = K_A . Q_B (16x16x16 f16):
// C-layout of S^T (n=quad*4+reg, m=lane&15) == B-frag layout for PV
// (O^T = V_A . P^T_B) -> no transpose. Bias: per-key precomputed bilinear
// weights (LDS) + 2 dword loads from paired-f16 table (L2-hot, 8 B/eval).
// grid 1536 = num(3)*b(8)*h(4)*mblock(16); wave w owns query row mblock*4+w.
// __launch_bounds__(256,3): cap ~168 VGPR > live (~120; kf+vf=64). Round-4
// lesson: never cap below live state (64-VGPR cap -> 72 GB spill, 26 ms).
// Round-5 lesson: keep t-loop FULLY unrolled (partial unroll made kf[t]/vf[t]
// dynamically indexed -> 15x VALU issue, 1172 us).
__global__ __launch_bounds__(256, 3) void k_attn(
    float* __restrict__ q_buf, const float* __restrict__ k_buf,
    const float* __restrict__ v_buf, const float* __restrict__ pos_buf,
    const __half2* __restrict__ tpad2) {
  int wg = blockIdx.x;
  int mblock = wg & 15;
  int h = (wg >> 4) & 3;
  int b = (wg >> 6) & 7;
  int num = wg >> 9;
  int nb = num * 8 + b;
  int tid = threadIdx.x;
  int lane = tid & 63;
  int wave = __builtin_amdgcn_readfirstlane(tid >> 6);
  int l15 = lane & 15;
  int quad = lane >> 4;

  __shared__ int s_off[256];        // per key: iy*128+ix
  __shared__ float4 s_w[256];       // per key: w00,w01,w10,w11
  {
    float py = pos_buf[(nb * 256 + tid) * 2 + 0];
    float px = pos_buf[(nb * 256 + tid) * 2 + 1];
    float by = 31.5f * (1.f - py);
    float bx = 31.5f * (1.f - px);
    float iyf = floorf(by), ixf = floorf(bx);
    float fy = by - iyf, fx = bx - ixf;
    s_off[tid] = (int)iyf * 128 + (int)ixf;
    float4 w;
    w.x = (1.f - fy) * (1.f - fx);
    w.y = (1.f - fy) * fx;
    w.z = fy * (1.f - fx);
    w.w = fy * fx;
    s_w[tid] = w;
  }
  __syncthreads();

  int hc = nb * 64 + h * 16;
  const float* kb = k_buf + hc * 256;
  const float* vb = v_buf + hc * 256;
  float* qb = q_buf + hc * 4096;
  const __half2* T = tpad2 + (num * 4 + h) * 16384;

  // K frags: A[n][c]: n = l15 + 16t, c = quad*4+j  (reused across 4 m-tiles)
  // V frags: A[c][n]: c = l15, n = 16t + quad*4+j  -> contiguous float4
  f16x4 kf[16], vf[16];
#pragma unroll
  for (int t = 0; t < 16; ++t) {
    int n = t * 16 + l15;
#pragma unroll
    for (int j = 0; j < 4; ++j)
      kf[t][j] = (_Float16)kb[(quad * 4 + j) * 256 + n];
    float4 vv = *(const float4*)(vb + l15 * 256 + t * 16 + quad * 4);
    vf[t][0] = (_Float16)vv.x; vf[t][1] = (_Float16)vv.y;
    vf[t][2] = (_Float16)vv.z; vf[t][3] = (_Float16)vv.w;
  }

#pragma unroll 1
  for (int mt = 0; mt < 4; ++mt) {
    int m = mblock * 256 + wave * 64 + mt * 16 + l15;
    int boff = (mblock * 4 + wave) * 128 + mt * 16 + l15;  // my*128 + mx
    f16x4 qf;
#pragma unroll
    for (int j = 0; j < 4; ++j)
      qf[j] = (_Float16)qb[(quad * 4 + j) * 4096 + m];

    f32x4 O = {0.f, 0.f, 0.f, 0.f};
    float L = 0.f;
#pragma unroll
    for (int t = 0; t < 16; ++t) {
      f32x4 Z = {0.f, 0.f, 0.f, 0.f};
      f32x4 S = __builtin_amdgcn_mfma_f32_16x16x16f16(kf[t], qf, Z, 0, 0, 0);
      f16x4 pf;
#pragma unroll
      for (int r = 0; r < 4; ++r) {
        int key = t * 16 + quad * 4 + r;
        int idx = s_off[key] + boff;
        float2 f0 = __half22float2(T[idx]);        // t00, t01
        float2 f1 = __half22float2(T[idx + 128]);  // t10, t11
        float4 w = s_w[key];
        float bias = w.x * f0.x + w.y * f0.y + w.z * f1.x + w.w * f1.y;
        float s = fminf(fmaf(S[r], 0.25f, bias), 10.f);
        float e = __expf(s);
        L += e;
        pf[r] = (_Float16)e;
      }
      O = __builtin_amdgcn_mfma_f32_16x16x16f16(vf[t], pf, O, 0, 0, 0);
    }
    L += __shfl_xor(L, 16);
    L += __shfl_xor(L, 32);
    float rinv = 1.f / L;
#pragma unroll
    for (int r = 0; r < 4; ++r)
      qb[(quad * 4 + r) * 4096 + m] = O[r] * rinv;  // in-place over q
  }
}

// ---- po conv fused with residual: out[l][b][64+o] = x_l[..] + sum_num conv
// grid 512 = lv(2) * b(8) * tile(32 of 128 pos). No atomics.
__global__ __launch_bounds__(256) void k_po(
    const float* __restrict__ attn_buf, const float* __restrict__ x1,
    const float* __restrict__ x2, const float* __restrict__ po_w,
    const float* __restrict__ po_b, float* __restrict__ out) {
  int wg = blockIdx.x;
  int tile = wg & 31;
  int b = (wg >> 5) & 7;
  int lv = wg >> 8;                 // 0 -> level1 (num0), 1 -> level2 (num1+2)
  int p0 = tile * 128;
  int tid = threadIdx.x;
  int lane = tid & 63;
  int og = __builtin_amdgcn_readfirstlane(tid >> 6);
  int o0 = og * 16;
  const float* xsrc = (lv == 0) ? x1 : x2;
  float acc[2][16];
#pragma unroll
  for (int i = 0; i < 16; ++i) {
    int o = o0 + i;
    float2 xv = *(const float2*)(xsrc + b * 524288 + (64 + o) * 4096 + p0 +
                                 lane * 2);
    float bsum = (lv == 0) ? po_b[o] : (po_b[64 + o] + po_b[128 + o]);
    acc[0][i] = xv.x + bsum;
    acc[1][i] = xv.y + bsum;
  }
  __shared__ float lx[16 * 128];
  int numA = (lv == 0) ? 0 : 1;
  int numB = (lv == 0) ? 0 : 2;
  for (int num = numA; num <= numB; ++num) {
    const float* abase = attn_buf + (num * 8 + b) * 262144;
    const float* w = po_w + num * 4096;
    for (int cc = 0; cc < 64; cc += 16) {
      __syncthreads();
#pragma unroll
      for (int r = 0; r < 2; ++r) {
        int idx = tid + r * 256;
        int c = idx >> 5, col4 = idx & 31;
        *(float4*)(lx + c * 128 + col4 * 4) =
            *(const float4*)(abase + (cc + c) * 4096 + p0 + col4 * 4);
      }
      __syncthreads();
#pragma unroll
      for (int c = 0; c < 16; ++c) {
        float2 xv = *(const float2*)(lx + c * 128 + lane * 2);
#pragma unroll
        for (int i = 0; i < 16; ++i) {
          float wv = w[(o0 + i) * 64 + cc + c];
          acc[0][i] += xv.x * wv;
          acc[1][i] += xv.y * wv;
        }
      }
    }
  }
  float* ob = out + ((lv + 1) * 8 + b) * 524288 + 64 * 4096;
#pragma unroll
  for (int i = 0; i < 16; ++i) {
    int o = o0 + i;
    float2 r2 = {acc[0][i], acc[1][i]};
    *(float2*)(ob + o * 4096 + p0 + lane * 2) = r2;
  }
}

extern "C" void kernel_launch(void* const* d_in, const int* in_sizes, int n_in,
                              void* d_out, int out_size, void* d_ws,
                              size_t ws_size, hipStream_t stream) {
  const float* x0 = (const float*)d_in[0];
  const float* x1 = (const float*)d_in[1];
  const float* x2 = (const float*)d_in[2];
  const float* pq_w = (const float*)d_in[3];
  const float* pq_b = (const float*)d_in[4];
  const float* dw_w = (const float*)d_in[5];
  const float* dw_b = (const float*)d_in[6];
  const float* ln_g = (const float*)d_in[7];
  const float* ln_b = (const float*)d_in[8];
  const float* pw_w = (const float*)d_in[9];
  const float* pk_w = (const float*)d_in[10];
  const float* pk_b = (const float*)d_in[11];
  const float* pv_w = (const float*)d_in[12];
  const float* pv_b = (const float*)d_in[13];
  const float* po_w = (const float*)d_in[14];
  const float* po_b = (const float*)d_in[15];
  const float* rpe = (const float*)d_in[16];
  float* out = (float*)d_out;
  float* ws = (float*)d_ws;

  // ws layout (floats): q/attn (in-place) 6291456, pos 12288, xs 393216,
  // k 393216, v 393216 -> 29,933,568 bytes (round-0-proven size).
  // tpad2 (196608 floats) aliases xs_buf: dead after k_kv; k_padrpe after.
  float* q_buf = ws;
  float* pos_buf = q_buf + 6291456;
  float* xs_buf = pos_buf + 12288;
  float* k_buf = xs_buf + 393216;
  float* v_buf = k_buf + 393216;
  __half2* tpad2 = (__half2*)xs_buf;

  hipLaunchKernelGGL(k_copy, dim3(8192), dim3(256), 0, stream, x0, x1, x2, out);
  hipLaunchKernelGGL(k_qconv, dim3(768), dim3(256), 0, stream, x1, x2, pq_w,
                     pq_b, q_buf);
  hipLaunchKernelGGL(k_offset, dim3(24), dim3(256), 0, stream, q_buf, dw_w,
                     dw_b, ln_g, ln_b, pw_w, pos_buf);
  hipLaunchKernelGGL(k_sample, dim3(192), dim3(256), 0, stream, x0, x1,
                     pos_buf, xs_buf);
  hipLaunchKernelGGL(k_kv, dim3(192), dim3(256), 0, stream, xs_buf, pk_w, pk_b,
                     pv_w, pv_b, k_buf, v_buf);
  hipLaunchKernelGGL(k_padrpe, dim3(1536), dim3(128), 0, stream, rpe, tpad2);
  hipLaunchKernelGGL(k_attn, dim3(1536), dim3(256), 0, stream, q_buf, k_buf,
                     v_buf, pos_buf, tpad2);
  hipLaunchKernelGGL(k_po, dim3(512), dim3(256), 0, stream, q_buf, x1, x2,
                     po_w, po_b, out);
}